// Round 1
// baseline (9423.751 us; speedup 1.0000x reference)
//
#include <hip/hip_runtime.h>

#define N_USER 50000
#define N_REST 20000
#define D_IN   512
#define HID    256
#define E_REV  500000
#define E_NEAR 250000

static inline int ceil_div(int a, int b) { return (a + b - 1) / b; }

// ---------------------------------------------------------------------------
// GEMM: C[M,256] = op(A)[M,K] @ B[K,256]; op = identity or relu (fused on load)
// A row-major [M,K], B row-major [K,256], C row-major [M,256].
// ---------------------------------------------------------------------------
#define BM 128
#define BN 64
#define BK 16
#define TM 8
#define TN 4

template<bool RELU_A>
__global__ __launch_bounds__(256) void gemm_rn(const float* __restrict__ A,
                                               const float* __restrict__ B,
                                               float* __restrict__ C,
                                               int M, int K) {
    __shared__ float As[BK][BM + 4];   // pad: row = 132 floats = 528B (16B-aligned)
    __shared__ float Bs[BK][BN + 4];   // pad: row = 68 floats = 272B (16B-aligned)

    const int tid = threadIdx.x;
    const int tx  = tid & 15;          // 0..15 -> TN-col group
    const int ty  = tid >> 4;          // 0..15 -> TM-row group
    const int bm  = blockIdx.x * BM;
    const int bn  = blockIdx.y * BN;

    // A staging: thread loads 2 float4: rows (tid>>2) and (tid>>2)+64, cols (tid&3)*4
    const int ar0 = tid >> 2;          // 0..63
    const int ac  = (tid & 3) * 4;     // 0,4,8,12
    // B staging: row tid>>4 (0..15), cols (tid&15)*4
    const int bkr = tid >> 4;
    const int bc  = (tid & 15) * 4;

    float acc[TM][TN];
#pragma unroll
    for (int i = 0; i < TM; i++)
#pragma unroll
        for (int j = 0; j < TN; j++) acc[i][j] = 0.f;

    for (int k0 = 0; k0 < K; k0 += BK) {
#pragma unroll
        for (int h = 0; h < 2; h++) {
            int r  = ar0 + h * 64;
            int gr = bm + r;
            float4 av = make_float4(0.f, 0.f, 0.f, 0.f);
            if (gr < M) av = *(const float4*)&A[(size_t)gr * K + k0 + ac];
            if (RELU_A) {
                av.x = fmaxf(av.x, 0.f); av.y = fmaxf(av.y, 0.f);
                av.z = fmaxf(av.z, 0.f); av.w = fmaxf(av.w, 0.f);
            }
            As[ac + 0][r] = av.x; As[ac + 1][r] = av.y;
            As[ac + 2][r] = av.z; As[ac + 3][r] = av.w;
        }
        {
            float4 bv = *(const float4*)&B[(size_t)(k0 + bkr) * 256 + bn + bc];
            *(float4*)&Bs[bkr][bc] = bv;
        }
        __syncthreads();

#pragma unroll
        for (int k = 0; k < BK; k++) {
            float a[TM], b[TN];
            *(float4*)&a[0] = *(const float4*)&As[k][ty * TM];
            *(float4*)&a[4] = *(const float4*)&As[k][ty * TM + 4];
            *(float4*)&b[0] = *(const float4*)&Bs[k][tx * TN];
#pragma unroll
            for (int i = 0; i < TM; i++)
#pragma unroll
                for (int j = 0; j < TN; j++)
                    acc[i][j] = fmaf(a[i], b[j], acc[i][j]);
        }
        __syncthreads();
    }

#pragma unroll
    for (int i = 0; i < TM; i++) {
        int gr = bm + ty * TM + i;
        if (gr < M) {
            float4 v = make_float4(acc[i][0], acc[i][1], acc[i][2], acc[i][3]);
            *(float4*)&C[(size_t)gr * 256 + bn + tx * TN] = v;
        }
    }
}

// ---------------------------------------------------------------------------
// Degree counting: one thread per edge, +1.0f into deg_s[src], deg_d[dst]
// ---------------------------------------------------------------------------
__global__ void degree_kernel(const int* __restrict__ src, const int* __restrict__ dst,
                              float* __restrict__ deg_s, float* __restrict__ deg_d, int E) {
    int e = blockIdx.x * blockDim.x + threadIdx.x;
    if (e >= E) return;
    atomicAdd(&deg_s[src[e]], 1.0f);
    atomicAdd(&deg_d[dst[e]], 1.0f);
}

// In-place: deg -> (deg+add) > 0 ? rsqrt(deg+add) : 0
__global__ void inv_kernel(float* __restrict__ deg, int n, float add) {
    int i = blockIdx.x * blockDim.x + threadIdx.x;
    if (i >= n) return;
    float d = deg[i] + add;
    deg[i] = (d > 0.f) ? rsqrtf(d) : 0.f;
}

// ---------------------------------------------------------------------------
// Aggregation-buffer initializers (write biases + self-loop term)
// grid = rows, block = 256 (one thread per column)
// ---------------------------------------------------------------------------
__global__ void init_rest(float* __restrict__ agg, const float* __restrict__ hwa,
                          const float* __restrict__ inv_ns, const float* __restrict__ inv_nd,
                          const float* __restrict__ b_ur, const float* __restrict__ b_rr) {
    int r = blockIdx.x, c = threadIdx.x;
    size_t idx = (size_t)r * HID + c;
    float self = inv_ns[r] * inv_nd[r];
    agg[idx] = b_ur[c] + b_rr[c] + hwa[idx] * self;
}

__global__ void init_user(float* __restrict__ agg, const float* __restrict__ b) {
    size_t idx = (size_t)blockIdx.x * HID + threadIdx.x;
    agg[idx] = b[threadIdx.x];
}

// ---------------------------------------------------------------------------
// Edge scatter: one wave per edge. Lane l handles cols 4l..4l+3 (float4 gather
// of hw[src] row, 4 fp32 global atomics into agg[dst] row).
// ---------------------------------------------------------------------------
__global__ void scatter_edges(const int* __restrict__ src, const int* __restrict__ dst,
                              const float* __restrict__ hw, float* __restrict__ agg,
                              const float* __restrict__ inv_s, const float* __restrict__ inv_d,
                              int E) {
    int wave = (blockIdx.x * blockDim.x + threadIdx.x) >> 6;
    int lane = threadIdx.x & 63;
    if (wave >= E) return;
    int s = src[wave], d = dst[wave];
    float nrm = inv_s[s] * inv_d[d];
    float4 v = *(const float4*)&hw[(size_t)s * HID + lane * 4];
    float* p = &agg[(size_t)d * HID + lane * 4];
    atomicAdd(p + 0, v.x * nrm);
    atomicAdd(p + 1, v.y * nrm);
    atomicAdd(p + 2, v.z * nrm);
    atomicAdd(p + 3, v.w * nrm);
}

// ---------------------------------------------------------------------------
extern "C" void kernel_launch(void* const* d_in, const int* in_sizes, int n_in,
                              void* d_out, int out_size, void* d_ws, size_t ws_size,
                              hipStream_t stream) {
    const float* x_user   = (const float*)d_in[0];
    const float* x_rest   = (const float*)d_in[1];
    const int*   rev_src  = (const int*)d_in[2];
    const int*   rev_dst  = (const int*)d_in[3];
    const int*   near_src = (const int*)d_in[4];
    const int*   near_dst = (const int*)d_in[5];
    const float* Win_user = (const float*)d_in[6];
    const float* Win_rest = (const float*)d_in[7];
    const float* W1_ur = (const float*)d_in[8];  const float* b1_ur = (const float*)d_in[9];
    const float* W1_ru = (const float*)d_in[10]; const float* b1_ru = (const float*)d_in[11];
    const float* W1_rr = (const float*)d_in[12]; const float* b1_rr = (const float*)d_in[13];
    const float* W2_ur = (const float*)d_in[14]; const float* b2_ur = (const float*)d_in[15];
    const float* W2_ru = (const float*)d_in[16]; const float* b2_ru = (const float*)d_in[17];
    const float* W2_rr = (const float*)d_in[18]; const float* b2_rr = (const float*)d_in[19];
    const float* Wout_user = (const float*)d_in[20];
    const float* Wout_rest = (const float*)d_in[21];

    // Workspace layout (fp32), total ~164 MB
    float* ws     = (float*)d_ws;
    float* hu     = ws;                               // N_USER*HID (also agg_user)
    float* hr     = hu  + (size_t)N_USER * HID;       // N_REST*HID (also agg_rest)
    float* hwu    = hr  + (size_t)N_REST * HID;       // N_USER*HID
    float* hwa    = hwu + (size_t)N_USER * HID;       // N_REST*HID
    float* hwb    = hwa + (size_t)N_REST * HID;       // N_REST*HID
    float* inv_us = hwb + (size_t)N_REST * HID;       // N_USER  (deg over rev_src)
    float* inv_rd = inv_us + N_USER;                  // N_REST  (deg over rev_dst)
    float* inv_ns = inv_rd + N_REST;                  // N_REST  (deg over near_src, +1)
    float* inv_nd = inv_ns + N_REST;                  // N_REST  (deg over near_dst, +1)

    // ---- degrees -> inverse-sqrt norms (in place) ----
    hipMemsetAsync(inv_us, 0, (size_t)(N_USER + 3 * N_REST) * sizeof(float), stream);
    degree_kernel<<<ceil_div(E_REV, 256), 256, 0, stream>>>(rev_src, rev_dst, inv_us, inv_rd, E_REV);
    degree_kernel<<<ceil_div(E_NEAR, 256), 256, 0, stream>>>(near_src, near_dst, inv_ns, inv_nd, E_NEAR);
    inv_kernel<<<ceil_div(N_USER, 256), 256, 0, stream>>>(inv_us, N_USER, 0.f);
    inv_kernel<<<ceil_div(N_REST, 256), 256, 0, stream>>>(inv_rd, N_REST, 0.f);
    inv_kernel<<<ceil_div(N_REST, 256), 256, 0, stream>>>(inv_ns, N_REST, 1.f);  // self-loop
    inv_kernel<<<ceil_div(N_REST, 256), 256, 0, stream>>>(inv_nd, N_REST, 1.f);  // self-loop

    // ---- input projections (no relu) ----
    gemm_rn<false><<<dim3(ceil_div(N_USER, BM), HID / BN), 256, 0, stream>>>(x_user, Win_user, hu, N_USER, D_IN);
    gemm_rn<false><<<dim3(ceil_div(N_REST, BM), HID / BN), 256, 0, stream>>>(x_rest, Win_rest, hr, N_REST, D_IN);

    // ---- two HeteroConv layers ----
    for (int layer = 0; layer < 2; layer++) {
        const float *Wur, *bur, *Wru, *bru, *Wrr, *brr;
        if (layer == 0) { Wur = W1_ur; bur = b1_ur; Wru = W1_ru; bru = b1_ru; Wrr = W1_rr; brr = b1_rr; }
        else            { Wur = W2_ur; bur = b2_ur; Wru = W2_ru; bru = b2_ru; Wrr = W2_rr; brr = b2_rr; }

        // projections; relu of previous layer fused into the A-load (layer 2 only)
        if (layer == 1) {
            gemm_rn<true><<<dim3(ceil_div(N_USER, BM), HID / BN), 256, 0, stream>>>(hu, Wur, hwu, N_USER, HID);
            gemm_rn<true><<<dim3(ceil_div(N_REST, BM), HID / BN), 256, 0, stream>>>(hr, Wrr, hwa, N_REST, HID);
            gemm_rn<true><<<dim3(ceil_div(N_REST, BM), HID / BN), 256, 0, stream>>>(hr, Wru, hwb, N_REST, HID);
        } else {
            gemm_rn<false><<<dim3(ceil_div(N_USER, BM), HID / BN), 256, 0, stream>>>(hu, Wur, hwu, N_USER, HID);
            gemm_rn<false><<<dim3(ceil_div(N_REST, BM), HID / BN), 256, 0, stream>>>(hr, Wrr, hwa, N_REST, HID);
            gemm_rn<false><<<dim3(ceil_div(N_REST, BM), HID / BN), 256, 0, stream>>>(hr, Wru, hwb, N_REST, HID);
        }

        // hu/hr no longer needed as inputs -> become aggregation buffers
        init_rest<<<N_REST, 256, 0, stream>>>(hr, hwa, inv_ns, inv_nd, bur, brr);
        init_user<<<N_USER, 256, 0, stream>>>(hu, bru);

        // relation ur: user->rest over rev edges
        scatter_edges<<<ceil_div(E_REV, 4), 256, 0, stream>>>(rev_src, rev_dst, hwu, hr, inv_us, inv_rd, E_REV);
        // relation rr: rest->rest over near edges
        scatter_edges<<<ceil_div(E_NEAR, 4), 256, 0, stream>>>(near_src, near_dst, hwa, hr, inv_ns, inv_nd, E_NEAR);
        // relation ru: rest->user over reversed rev edges
        scatter_edges<<<ceil_div(E_REV, 4), 256, 0, stream>>>(rev_dst, rev_src, hwb, hu, inv_rd, inv_us, E_REV);
    }

    // ---- output projections (relu of layer-2 output fused into A-load) ----
    float* out_user = (float*)d_out;
    float* out_rest = out_user + (size_t)N_USER * HID;
    gemm_rn<true><<<dim3(ceil_div(N_USER, BM), HID / BN), 256, 0, stream>>>(hu, Wout_user, out_user, N_USER, HID);
    gemm_rn<true><<<dim3(ceil_div(N_REST, BM), HID / BN), 256, 0, stream>>>(hr, Wout_rest, out_rest, N_REST, HID);
}

// Round 2
// 1544.112 us; speedup vs baseline: 6.1030x; 6.1030x over previous
//
#include <hip/hip_runtime.h>

#define N_USER 50000
#define N_REST 20000
#define D_IN   512
#define HID    256
#define E_REV  500000
#define E_NEAR 250000

static inline int ceil_div(int a, int b) { return (a + b - 1) / b; }

// ---------------------------------------------------------------------------
// GEMM: C[M,256] = op(A)[M,K] @ B[K,256], optional row-scale S[row] on output.
// A row-major [M,K], B row-major [K,256], C row-major [M,256].
// ---------------------------------------------------------------------------
#define BM 128
#define BN 64
#define BK 16
#define TM 8
#define TN 4

template<bool RELU_A, bool SCALE>
__global__ __launch_bounds__(256) void gemm_rn(const float* __restrict__ A,
                                               const float* __restrict__ B,
                                               float* __restrict__ C,
                                               const float* __restrict__ S,
                                               int M, int K) {
    __shared__ float As[BK][BM + 4];
    __shared__ float Bs[BK][BN + 4];

    const int tid = threadIdx.x;
    const int tx  = tid & 15;
    const int ty  = tid >> 4;
    const int bm  = blockIdx.x * BM;
    const int bn  = blockIdx.y * BN;

    const int ar0 = tid >> 2;
    const int ac  = (tid & 3) * 4;
    const int bkr = tid >> 4;
    const int bc  = (tid & 15) * 4;

    float acc[TM][TN];
#pragma unroll
    for (int i = 0; i < TM; i++)
#pragma unroll
        for (int j = 0; j < TN; j++) acc[i][j] = 0.f;

    for (int k0 = 0; k0 < K; k0 += BK) {
#pragma unroll
        for (int h = 0; h < 2; h++) {
            int r  = ar0 + h * 64;
            int gr = bm + r;
            float4 av = make_float4(0.f, 0.f, 0.f, 0.f);
            if (gr < M) av = *(const float4*)&A[(size_t)gr * K + k0 + ac];
            if (RELU_A) {
                av.x = fmaxf(av.x, 0.f); av.y = fmaxf(av.y, 0.f);
                av.z = fmaxf(av.z, 0.f); av.w = fmaxf(av.w, 0.f);
            }
            As[ac + 0][r] = av.x; As[ac + 1][r] = av.y;
            As[ac + 2][r] = av.z; As[ac + 3][r] = av.w;
        }
        *(float4*)&Bs[bkr][bc] = *(const float4*)&B[(size_t)(k0 + bkr) * 256 + bn + bc];
        __syncthreads();

#pragma unroll
        for (int k = 0; k < BK; k++) {
            float a[TM], b[TN];
            *(float4*)&a[0] = *(const float4*)&As[k][ty * TM];
            *(float4*)&a[4] = *(const float4*)&As[k][ty * TM + 4];
            *(float4*)&b[0] = *(const float4*)&Bs[k][tx * TN];
#pragma unroll
            for (int i = 0; i < TM; i++)
#pragma unroll
                for (int j = 0; j < TN; j++)
                    acc[i][j] = fmaf(a[i], b[j], acc[i][j]);
        }
        __syncthreads();
    }

#pragma unroll
    for (int i = 0; i < TM; i++) {
        int gr = bm + ty * TM + i;
        if (gr < M) {
            float sc = SCALE ? S[gr] : 1.f;
            float4 v = make_float4(acc[i][0] * sc, acc[i][1] * sc,
                                   acc[i][2] * sc, acc[i][3] * sc);
            *(float4*)&C[(size_t)gr * 256 + bn + tx * TN] = v;
        }
    }
}

// ---------------------------------------------------------------------------
// CSR build: count -> exclusive scan -> fill (grouped by destination).
// ---------------------------------------------------------------------------
__global__ void count_pair(const int* __restrict__ a, const int* __restrict__ b,
                           int* __restrict__ cnt_a, int* __restrict__ cnt_b, int E) {
    int e = blockIdx.x * blockDim.x + threadIdx.x;
    if (e >= E) return;
    atomicAdd(&cnt_a[a[e]], 1);
    atomicAdd(&cnt_b[b[e]], 1);
}

// inv[i] = (cnt[i]+add) > 0 ? rsqrt(cnt[i]+add) : 0   (add = 1 for self-loop rels)
__global__ void inv_from_cnt(const int* __restrict__ cnt, float* __restrict__ inv,
                             int n, float add) {
    int i = blockIdx.x * blockDim.x + threadIdx.x;
    if (i >= n) return;
    float d = (float)cnt[i] + add;
    inv[i] = (d > 0.f) ? rsqrtf(d) : 0.f;
}

// Single-block exclusive scan: ptr[0..n] from cnt[0..n-1]; ptr[n] = total.
__global__ __launch_bounds__(1024) void scan_excl(const int* __restrict__ cnt,
                                                  int* __restrict__ ptr, int n) {
    __shared__ int wsum[16];
    __shared__ int carry_s;
    const int tid = threadIdx.x, lane = tid & 63, wid = tid >> 6;
    if (tid == 0) carry_s = 0;
    __syncthreads();
    for (int base = 0; base < n; base += 1024) {
        int i = base + tid;
        int v = (i < n) ? cnt[i] : 0;
        int x = v;
#pragma unroll
        for (int off = 1; off < 64; off <<= 1) {
            int y = __shfl_up(x, off, 64);
            if (lane >= off) x += y;
        }
        if (lane == 63) wsum[wid] = x;
        __syncthreads();
        if (wid == 0 && lane < 16) {
            int w = wsum[lane];
#pragma unroll
            for (int off = 1; off < 16; off <<= 1) {
                int y = __shfl_up(w, off, 16);
                if (lane >= off) w += y;
            }
            wsum[lane] = w;
        }
        __syncthreads();
        int wave_off = (wid > 0) ? wsum[wid - 1] : 0;
        if (i < n) ptr[i] = carry_s + wave_off + (x - v);
        __syncthreads();
        if (tid == 0) carry_s += wsum[15];
        __syncthreads();
    }
    if (threadIdx.x == 0) ptr[n] = carry_s;
}

// Fill CSR for rev edges: grouped-by-rev_dst (src stored) and grouped-by-rev_src.
__global__ void fill_rev(const int* __restrict__ rsrc, const int* __restrict__ rdst,
                         const int* __restrict__ ptr_ur, int* __restrict__ cur_ur,
                         int* __restrict__ csr_ur,
                         const int* __restrict__ ptr_ru, int* __restrict__ cur_ru,
                         int* __restrict__ csr_ru, int E) {
    int e = blockIdx.x * blockDim.x + threadIdx.x;
    if (e >= E) return;
    int s = rsrc[e], d = rdst[e];
    csr_ur[ptr_ur[d] + atomicAdd(&cur_ur[d], 1)] = s;
    csr_ru[ptr_ru[s] + atomicAdd(&cur_ru[s], 1)] = d;
}

__global__ void fill_one(const int* __restrict__ src, const int* __restrict__ dst,
                         const int* __restrict__ ptr, int* __restrict__ cur,
                         int* __restrict__ csr, int E) {
    int e = blockIdx.x * blockDim.x + threadIdx.x;
    if (e >= E) return;
    int d = dst[e];
    csr[ptr[d] + atomicAdd(&cur[d], 1)] = src[e];
}

// ---------------------------------------------------------------------------
// Gather aggregation. One wave per destination row; lane l holds cols 4l..4l+3.
// Sources are pre-scaled by src-side norm in the GEMM epilogue.
// out_rest = b_ur + b_rr + inv_rd[r]*sum_ur(hwu) + inv_nd[r]*(hwa[r] + sum_rr(hwa))
// ---------------------------------------------------------------------------
__device__ __forceinline__ void acc_rows(const int* __restrict__ csr, int beg, int end,
                                         const float* __restrict__ hw, int c, float4& acc) {
    int e = beg;
    for (; e + 1 < end; e += 2) {
        int s0 = csr[e], s1 = csr[e + 1];
        float4 v0 = *(const float4*)&hw[(size_t)s0 * HID + c];
        float4 v1 = *(const float4*)&hw[(size_t)s1 * HID + c];
        acc.x += v0.x + v1.x; acc.y += v0.y + v1.y;
        acc.z += v0.z + v1.z; acc.w += v0.w + v1.w;
    }
    if (e < end) {
        int s = csr[e];
        float4 v = *(const float4*)&hw[(size_t)s * HID + c];
        acc.x += v.x; acc.y += v.y; acc.z += v.z; acc.w += v.w;
    }
}

__global__ __launch_bounds__(256) void rest_agg(
    const int* __restrict__ ptr_ur, const int* __restrict__ csr_ur, const float* __restrict__ hwu,
    const int* __restrict__ ptr_rr, const int* __restrict__ csr_rr, const float* __restrict__ hwa,
    const float* __restrict__ inv_rd, const float* __restrict__ inv_nd,
    const float* __restrict__ b_ur, const float* __restrict__ b_rr,
    float* __restrict__ out) {
    int r = (blockIdx.x * blockDim.x + threadIdx.x) >> 6;
    int c = (threadIdx.x & 63) * 4;
    if (r >= N_REST) return;

    float4 au = make_float4(0.f, 0.f, 0.f, 0.f);
    acc_rows(csr_ur, ptr_ur[r], ptr_ur[r + 1], hwu, c, au);

    float4 ar = *(const float4*)&hwa[(size_t)r * HID + c];   // self-loop (pre-scaled inv_ns)
    acc_rows(csr_rr, ptr_rr[r], ptr_rr[r + 1], hwa, c, ar);

    float sd = inv_rd[r], sn = inv_nd[r];
    float4 bu = *(const float4*)&b_ur[c];
    float4 br = *(const float4*)&b_rr[c];
    float4 o;
    o.x = bu.x + br.x + sd * au.x + sn * ar.x;
    o.y = bu.y + br.y + sd * au.y + sn * ar.y;
    o.z = bu.z + br.z + sd * au.z + sn * ar.z;
    o.w = bu.w + br.w + sd * au.w + sn * ar.w;
    *(float4*)&out[(size_t)r * HID + c] = o;
}

__global__ __launch_bounds__(256) void user_agg(
    const int* __restrict__ ptr_ru, const int* __restrict__ csr_ru, const float* __restrict__ hwb,
    const float* __restrict__ inv_us, const float* __restrict__ b_ru,
    float* __restrict__ out) {
    int u = (blockIdx.x * blockDim.x + threadIdx.x) >> 6;
    int c = (threadIdx.x & 63) * 4;
    if (u >= N_USER) return;

    float4 a = make_float4(0.f, 0.f, 0.f, 0.f);
    acc_rows(csr_ru, ptr_ru[u], ptr_ru[u + 1], hwb, c, a);

    float su = inv_us[u];
    float4 b = *(const float4*)&b_ru[c];
    float4 o;
    o.x = b.x + su * a.x; o.y = b.y + su * a.y;
    o.z = b.z + su * a.z; o.w = b.w + su * a.w;
    *(float4*)&out[(size_t)u * HID + c] = o;
}

// ---------------------------------------------------------------------------
extern "C" void kernel_launch(void* const* d_in, const int* in_sizes, int n_in,
                              void* d_out, int out_size, void* d_ws, size_t ws_size,
                              hipStream_t stream) {
    const float* x_user   = (const float*)d_in[0];
    const float* x_rest   = (const float*)d_in[1];
    const int*   rev_src  = (const int*)d_in[2];
    const int*   rev_dst  = (const int*)d_in[3];
    const int*   near_src = (const int*)d_in[4];
    const int*   near_dst = (const int*)d_in[5];
    const float* Win_user = (const float*)d_in[6];
    const float* Win_rest = (const float*)d_in[7];
    const float* W1_ur = (const float*)d_in[8];  const float* b1_ur = (const float*)d_in[9];
    const float* W1_ru = (const float*)d_in[10]; const float* b1_ru = (const float*)d_in[11];
    const float* W1_rr = (const float*)d_in[12]; const float* b1_rr = (const float*)d_in[13];
    const float* W2_ur = (const float*)d_in[14]; const float* b2_ur = (const float*)d_in[15];
    const float* W2_ru = (const float*)d_in[16]; const float* b2_ru = (const float*)d_in[17];
    const float* W2_rr = (const float*)d_in[18]; const float* b2_rr = (const float*)d_in[19];
    const float* Wout_user = (const float*)d_in[20];
    const float* Wout_rest = (const float*)d_in[21];

    // ---- workspace layout ----
    float* hu     = (float*)d_ws;                     // N_USER*HID (agg_user too)
    float* hr     = hu  + (size_t)N_USER * HID;       // N_REST*HID (agg_rest too)
    float* hwu    = hr  + (size_t)N_REST * HID;       // N_USER*HID
    float* hwa    = hwu + (size_t)N_USER * HID;       // N_REST*HID
    float* hwb    = hwa + (size_t)N_REST * HID;       // N_REST*HID
    float* inv_us = hwb + (size_t)N_REST * HID;       // N_USER
    float* inv_rd = inv_us + N_USER;                  // N_REST
    float* inv_ns = inv_rd + N_REST;                  // N_REST
    float* inv_nd = inv_ns + N_REST;                  // N_REST
    int*   cnt_ur = (int*)(inv_nd + N_REST);          // N_REST   (deg rev_dst)
    int*   cnt_ru = cnt_ur + N_REST;                  // N_USER   (deg rev_src)
    int*   cnt_rr = cnt_ru + N_USER;                  // N_REST   (deg near_dst)
    int*   cnt_ns = cnt_rr + N_REST;                  // N_REST   (deg near_src)
    int*   ptr_ur = cnt_ns + N_REST;                  // N_REST+1
    int*   ptr_ru = ptr_ur + N_REST + 1;              // N_USER+1
    int*   ptr_rr = ptr_ru + N_USER + 1;              // N_REST+1
    int*   csr_ur = ptr_rr + N_REST + 1;              // E_REV  (src grouped by rev_dst)
    int*   csr_ru = csr_ur + E_REV;                   // E_REV  (dst grouped by rev_src)
    int*   csr_rr = csr_ru + E_REV;                   // E_NEAR (src grouped by near_dst)

    // ---- CSR build + norms (counts double as degrees) ----
    hipMemsetAsync(cnt_ur, 0, (size_t)(3 * N_REST + N_USER) * sizeof(int), stream);
    count_pair<<<ceil_div(E_REV, 256), 256, 0, stream>>>(rev_src, rev_dst, cnt_ru, cnt_ur, E_REV);
    count_pair<<<ceil_div(E_NEAR, 256), 256, 0, stream>>>(near_src, near_dst, cnt_ns, cnt_rr, E_NEAR);
    inv_from_cnt<<<ceil_div(N_USER, 256), 256, 0, stream>>>(cnt_ru, inv_us, N_USER, 0.f);
    inv_from_cnt<<<ceil_div(N_REST, 256), 256, 0, stream>>>(cnt_ur, inv_rd, N_REST, 0.f);
    inv_from_cnt<<<ceil_div(N_REST, 256), 256, 0, stream>>>(cnt_ns, inv_ns, N_REST, 1.f);
    inv_from_cnt<<<ceil_div(N_REST, 256), 256, 0, stream>>>(cnt_rr, inv_nd, N_REST, 1.f);
    scan_excl<<<1, 1024, 0, stream>>>(cnt_ur, ptr_ur, N_REST);
    scan_excl<<<1, 1024, 0, stream>>>(cnt_ru, ptr_ru, N_USER);
    scan_excl<<<1, 1024, 0, stream>>>(cnt_rr, ptr_rr, N_REST);
    hipMemsetAsync(cnt_ur, 0, (size_t)(2 * N_REST + N_USER) * sizeof(int), stream);  // cnt_ur,cnt_ru,cnt_rr
    fill_rev<<<ceil_div(E_REV, 256), 256, 0, stream>>>(rev_src, rev_dst,
                                                       ptr_ur, cnt_ur, csr_ur,
                                                       ptr_ru, cnt_ru, csr_ru, E_REV);
    fill_one<<<ceil_div(E_NEAR, 256), 256, 0, stream>>>(near_src, near_dst,
                                                        ptr_rr, cnt_rr, csr_rr, E_NEAR);

    // ---- input projections ----
    gemm_rn<false, false><<<dim3(ceil_div(N_USER, BM), HID / BN), 256, 0, stream>>>(x_user, Win_user, hu, nullptr, N_USER, D_IN);
    gemm_rn<false, false><<<dim3(ceil_div(N_REST, BM), HID / BN), 256, 0, stream>>>(x_rest, Win_rest, hr, nullptr, N_REST, D_IN);

    // ---- two HeteroConv layers ----
    for (int layer = 0; layer < 2; layer++) {
        const float *Wur, *bur, *Wru, *bru, *Wrr, *brr;
        if (layer == 0) { Wur = W1_ur; bur = b1_ur; Wru = W1_ru; bru = b1_ru; Wrr = W1_rr; brr = b1_rr; }
        else            { Wur = W2_ur; bur = b2_ur; Wru = W2_ru; bru = b2_ru; Wrr = W2_rr; brr = b2_rr; }

        // projections, src-side norm fused into epilogue; relu of prev layer fused on load
        dim3 gu(ceil_div(N_USER, BM), HID / BN), gr_(ceil_div(N_REST, BM), HID / BN);
        if (layer == 1) {
            gemm_rn<true, true><<<gu, 256, 0, stream>>>(hu, Wur, hwu, inv_us, N_USER, HID);
            gemm_rn<true, true><<<gr_, 256, 0, stream>>>(hr, Wrr, hwa, inv_ns, N_REST, HID);
            gemm_rn<true, true><<<gr_, 256, 0, stream>>>(hr, Wru, hwb, inv_rd, N_REST, HID);
        } else {
            gemm_rn<false, true><<<gu, 256, 0, stream>>>(hu, Wur, hwu, inv_us, N_USER, HID);
            gemm_rn<false, true><<<gr_, 256, 0, stream>>>(hr, Wrr, hwa, inv_ns, N_REST, HID);
            gemm_rn<false, true><<<gr_, 256, 0, stream>>>(hr, Wru, hwb, inv_rd, N_REST, HID);
        }

        rest_agg<<<ceil_div(N_REST * 64, 256), 256, 0, stream>>>(ptr_ur, csr_ur, hwu,
                                                                 ptr_rr, csr_rr, hwa,
                                                                 inv_rd, inv_nd, bur, brr, hr);
        user_agg<<<ceil_div(N_USER * 64, 256), 256, 0, stream>>>(ptr_ru, csr_ru, hwb,
                                                                 inv_us, bru, hu);
    }

    // ---- output projections ----
    float* out_user = (float*)d_out;
    float* out_rest = out_user + (size_t)N_USER * HID;
    gemm_rn<true, false><<<dim3(ceil_div(N_USER, BM), HID / BN), 256, 0, stream>>>(hu, Wout_user, out_user, nullptr, N_USER, HID);
    gemm_rn<true, false><<<dim3(ceil_div(N_REST, BM), HID / BN), 256, 0, stream>>>(hr, Wout_rest, out_rest, nullptr, N_REST, HID);
}

// Round 3
// 897.718 us; speedup vs baseline: 10.4975x; 1.7200x over previous
//
#include <hip/hip_runtime.h>

#define N_USER 50000
#define N_REST 20000
#define D_IN   512
#define HID    256
#define E_REV  500000
#define E_NEAR 250000
#define MU_PAD 50048   // ceil(50000/128)*128
#define MR_PAD 20096   // ceil(20000/128)*128

static inline int ceil_div(int a, int b) { return (a + b - 1) / b; }

typedef _Float16 f16x8 __attribute__((ext_vector_type(8)));
typedef _Float16 f16x4 __attribute__((ext_vector_type(4)));
typedef float    f32x4 __attribute__((ext_vector_type(4)));

typedef const __attribute__((address_space(1))) void* gaddr_t;
typedef __attribute__((address_space(3))) void*       saddr_t;

// ---------------------------------------------------------------------------
// f16 MFMA GEMM: C[M,256] = A[M,K]f16 @ Bt[256,K]f16^T
// BM=128, BN=128, BK=32; 4 waves; wave w -> rows w*32..w*32+31, all 128 cols.
// Optional row-scale S (fp32) and f16 output. fp32 accumulate.
// ---------------------------------------------------------------------------
template<bool SCALE, bool OUT16>
__global__ __launch_bounds__(256) void gemm_f16(const _Float16* __restrict__ A,
                                                const _Float16* __restrict__ Bt,
                                                void* __restrict__ Cout,
                                                const float* __restrict__ S,
                                                int M, int K) {
    __shared__ _Float16 As[128][32];   // 8 KB
    __shared__ _Float16 Bs[128][32];   // 8 KB

    const int tid  = threadIdx.x;
    const int wave = tid >> 6, lane = tid & 63;
    const int bm = blockIdx.x * 128;
    const int bn = blockIdx.y * 128;

    // staging: lane l -> row (l>>2), 16B chunk (l&3); LDS dest = base + l*16
    const int srow = lane >> 2;
    const int scol = (lane & 3) * 8;

    const _Float16* Ag0 = A  + (size_t)(bm + wave * 16 + srow) * K + scol;
    const _Float16* Ag1 = Ag0 + (size_t)64 * K;
    const _Float16* Bg0 = Bt + (size_t)(bn + wave * 16 + srow) * K + scol;
    const _Float16* Bg1 = Bg0 + (size_t)64 * K;
    _Float16* lA0 = &As[wave * 16][0];
    _Float16* lA1 = &As[wave * 16 + 64][0];
    _Float16* lB0 = &Bs[wave * 16][0];
    _Float16* lB1 = &Bs[wave * 16 + 64][0];

    f32x4 acc[2][8];
#pragma unroll
    for (int i = 0; i < 2; i++)
#pragma unroll
        for (int j = 0; j < 8; j++) acc[i][j] = (f32x4){0.f, 0.f, 0.f, 0.f};

    const int fm = wave * 32 + (lane & 15);   // A frag rows: fm, fm+16
    const int fn = lane & 15;                 // B frag row within 16-tile
    const int qk = (lane >> 4) * 8;           // k-offset of this lane's quad

    for (int k0 = 0; k0 < K; k0 += 32) {
        __builtin_amdgcn_global_load_lds((gaddr_t)(Ag0 + k0), (saddr_t)lA0, 16, 0, 0);
        __builtin_amdgcn_global_load_lds((gaddr_t)(Ag1 + k0), (saddr_t)lA1, 16, 0, 0);
        __builtin_amdgcn_global_load_lds((gaddr_t)(Bg0 + k0), (saddr_t)lB0, 16, 0, 0);
        __builtin_amdgcn_global_load_lds((gaddr_t)(Bg1 + k0), (saddr_t)lB1, 16, 0, 0);
        __syncthreads();

        f16x8 af[2], bf[8];
        af[0] = *(const f16x8*)&As[fm][qk];
        af[1] = *(const f16x8*)&As[fm + 16][qk];
#pragma unroll
        for (int j = 0; j < 8; j++)
            bf[j] = *(const f16x8*)&Bs[j * 16 + fn][qk];

#pragma unroll
        for (int i = 0; i < 2; i++)
#pragma unroll
            for (int j = 0; j < 8; j++)
                acc[i][j] = __builtin_amdgcn_mfma_f32_16x16x32_f16(af[i], bf[j], acc[i][j], 0, 0, 0);
        __syncthreads();
    }

    // C/D layout: col = lane&15, rows = quad*4 + 0..3
#pragma unroll
    for (int i = 0; i < 2; i++) {
        int row0 = bm + wave * 32 + i * 16 + (lane >> 4) * 4;
#pragma unroll
        for (int j = 0; j < 8; j++) {
            int col = bn + j * 16 + (lane & 15);
#pragma unroll
            for (int rr = 0; rr < 4; rr++) {
                int gr = row0 + rr;
                float v = acc[i][j][rr];
                if (SCALE) v *= S[gr];
                if (OUT16) {
                    ((_Float16*)Cout)[(size_t)gr * HID + col] = (_Float16)v;
                } else {
                    if (gr < M) ((float*)Cout)[(size_t)gr * HID + col] = v;
                }
            }
        }
    }
}

// ---------------------------------------------------------------------------
// fp32 -> f16 conversion (8 elems/thread); n divisible by 8
// ---------------------------------------------------------------------------
__global__ void cvt_f16(const float* __restrict__ in, _Float16* __restrict__ out, int n) {
    int i = (blockIdx.x * blockDim.x + threadIdx.x) * 8;
    if (i >= n) return;
    float4 a = *(const float4*)&in[i];
    float4 b = *(const float4*)&in[i + 4];
    f16x8 o = {(_Float16)a.x, (_Float16)a.y, (_Float16)a.z, (_Float16)a.w,
               (_Float16)b.x, (_Float16)b.y, (_Float16)b.z, (_Float16)b.w};
    *(f16x8*)&out[i] = o;
}

// Weight prep: W[K][256] fp32 -> Wt[256][K] f16 (batched over 10 matrices)
struct WJobs { const float* w[10]; _Float16* wt[10]; int K[10]; };
__global__ void wprep(WJobs jb) {
    int m = blockIdx.y;
    const float* w = jb.w[m];
    _Float16* wt = jb.wt[m];
    int K = jb.K[m];
    int o = blockIdx.x * 256 + threadIdx.x;
    if (o >= K * 256) return;
    int n = (K == 512) ? (o >> 9) : (o >> 8);
    int k = o & (K - 1);
    wt[o] = (_Float16)w[(size_t)k * 256 + n];
}

// ---------------------------------------------------------------------------
// CSR build: count -> scan -> fill
// ---------------------------------------------------------------------------
__global__ void count_pair(const int* __restrict__ a, const int* __restrict__ b,
                           int* __restrict__ cnt_a, int* __restrict__ cnt_b, int E) {
    int e = blockIdx.x * blockDim.x + threadIdx.x;
    if (e >= E) return;
    atomicAdd(&cnt_a[a[e]], 1);
    atomicAdd(&cnt_b[b[e]], 1);
}

__device__ __forceinline__ float inv_deg(int c, float add) {
    float d = (float)c + add;
    return (d > 0.f) ? rsqrtf(d) : 0.f;
}

__global__ void inv_all(const int* __restrict__ cnt_ru, const int* __restrict__ cnt_ur,
                        const int* __restrict__ cnt_ns, const int* __restrict__ cnt_rr,
                        float* __restrict__ inv_us, float* __restrict__ inv_rd,
                        float* __restrict__ inv_ns, float* __restrict__ inv_nd) {
    int i = blockIdx.x * blockDim.x + threadIdx.x;
    if (i < N_USER) inv_us[i] = inv_deg(cnt_ru[i], 0.f);
    if (i < N_REST) {
        inv_rd[i] = inv_deg(cnt_ur[i], 0.f);
        inv_ns[i] = inv_deg(cnt_ns[i], 1.f);
        inv_nd[i] = inv_deg(cnt_rr[i], 1.f);
    }
}

__global__ __launch_bounds__(1024) void scan_excl(const int* __restrict__ cnt,
                                                  int* __restrict__ ptr, int n) {
    __shared__ int wsum[16];
    __shared__ int carry_s;
    const int tid = threadIdx.x, lane = tid & 63, wid = tid >> 6;
    if (tid == 0) carry_s = 0;
    __syncthreads();
    for (int base = 0; base < n; base += 1024) {
        int i = base + tid;
        int v = (i < n) ? cnt[i] : 0;
        int x = v;
#pragma unroll
        for (int off = 1; off < 64; off <<= 1) {
            int y = __shfl_up(x, off, 64);
            if (lane >= off) x += y;
        }
        if (lane == 63) wsum[wid] = x;
        __syncthreads();
        if (wid == 0 && lane < 16) {
            int w = wsum[lane];
#pragma unroll
            for (int off = 1; off < 16; off <<= 1) {
                int y = __shfl_up(w, off, 16);
                if (lane >= off) w += y;
            }
            wsum[lane] = w;
        }
        __syncthreads();
        int wave_off = (wid > 0) ? wsum[wid - 1] : 0;
        if (i < n) ptr[i] = carry_s + wave_off + (x - v);
        __syncthreads();
        if (tid == 0) carry_s += wsum[15];
        __syncthreads();
    }
    if (threadIdx.x == 0) ptr[n] = carry_s;
}

__global__ void fill_rev(const int* __restrict__ rsrc, const int* __restrict__ rdst,
                         const int* __restrict__ ptr_ur, int* __restrict__ cur_ur,
                         int* __restrict__ csr_ur,
                         const int* __restrict__ ptr_ru, int* __restrict__ cur_ru,
                         int* __restrict__ csr_ru, int E) {
    int e = blockIdx.x * blockDim.x + threadIdx.x;
    if (e >= E) return;
    int s = rsrc[e], d = rdst[e];
    csr_ur[ptr_ur[d] + atomicAdd(&cur_ur[d], 1)] = s;
    csr_ru[ptr_ru[s] + atomicAdd(&cur_ru[s], 1)] = d;
}

__global__ void fill_one(const int* __restrict__ src, const int* __restrict__ dst,
                         const int* __restrict__ ptr, int* __restrict__ cur,
                         int* __restrict__ csr, int E) {
    int e = blockIdx.x * blockDim.x + threadIdx.x;
    if (e >= E) return;
    int d = dst[e];
    csr[ptr[d] + atomicAdd(&cur[d], 1)] = src[e];
}

// ---------------------------------------------------------------------------
// Gather aggregation, f16 in / f16 out (relu applied). One wave per dst row;
// lane l holds cols 4l..4l+3 (fp32 accumulate).
// ---------------------------------------------------------------------------
__device__ __forceinline__ void acc_rows16(const int* __restrict__ csr, int beg, int end,
                                           const _Float16* __restrict__ hw, int c, f32x4& acc) {
    int e = beg;
    for (; e + 1 < end; e += 2) {
        f16x4 v0 = *(const f16x4*)&hw[(size_t)csr[e]     * HID + c];
        f16x4 v1 = *(const f16x4*)&hw[(size_t)csr[e + 1] * HID + c];
#pragma unroll
        for (int r = 0; r < 4; r++) acc[r] += (float)v0[r] + (float)v1[r];
    }
    if (e < end) {
        f16x4 v = *(const f16x4*)&hw[(size_t)csr[e] * HID + c];
#pragma unroll
        for (int r = 0; r < 4; r++) acc[r] += (float)v[r];
    }
}

__global__ __launch_bounds__(256) void rest_agg(
    const int* __restrict__ ptr_ur, const int* __restrict__ csr_ur, const _Float16* __restrict__ hwu,
    const int* __restrict__ ptr_rr, const int* __restrict__ csr_rr, const _Float16* __restrict__ hwa,
    const float* __restrict__ inv_rd, const float* __restrict__ inv_nd,
    const float* __restrict__ b_ur, const float* __restrict__ b_rr,
    _Float16* __restrict__ out) {
    int row = (blockIdx.x * blockDim.x + threadIdx.x) >> 6;
    int c = (threadIdx.x & 63) * 4;
    if (row >= N_REST) return;

    f32x4 au = (f32x4){0.f, 0.f, 0.f, 0.f};
    acc_rows16(csr_ur, ptr_ur[row], ptr_ur[row + 1], hwu, c, au);

    f32x4 ar = (f32x4){0.f, 0.f, 0.f, 0.f};
    {   // self-loop term (hwa pre-scaled by inv_ns)
        f16x4 v = *(const f16x4*)&hwa[(size_t)row * HID + c];
#pragma unroll
        for (int r = 0; r < 4; r++) ar[r] = (float)v[r];
    }
    acc_rows16(csr_rr, ptr_rr[row], ptr_rr[row + 1], hwa, c, ar);

    float sd = inv_rd[row], sn = inv_nd[row];
    f32x4 bu = *(const f32x4*)&b_ur[c];
    f32x4 br = *(const f32x4*)&b_rr[c];
    f16x4 oh;
#pragma unroll
    for (int r = 0; r < 4; r++) {
        float o = bu[r] + br[r] + sd * au[r] + sn * ar[r];
        oh[r] = (_Float16)fmaxf(o, 0.f);          // relu fused
    }
    *(f16x4*)&out[(size_t)row * HID + c] = oh;
}

__global__ __launch_bounds__(256) void user_agg(
    const int* __restrict__ ptr_ru, const int* __restrict__ csr_ru, const _Float16* __restrict__ hwb,
    const float* __restrict__ inv_us, const float* __restrict__ b_ru,
    _Float16* __restrict__ out) {
    int row = (blockIdx.x * blockDim.x + threadIdx.x) >> 6;
    int c = (threadIdx.x & 63) * 4;
    if (row >= N_USER) return;

    f32x4 a = (f32x4){0.f, 0.f, 0.f, 0.f};
    acc_rows16(csr_ru, ptr_ru[row], ptr_ru[row + 1], hwb, c, a);

    float su = inv_us[row];
    f32x4 b = *(const f32x4*)&b_ru[c];
    f16x4 oh;
#pragma unroll
    for (int r = 0; r < 4; r++)
        oh[r] = (_Float16)fmaxf(b[r] + su * a[r], 0.f);   // relu fused
    *(f16x4*)&out[(size_t)row * HID + c] = oh;
}

// ---------------------------------------------------------------------------
extern "C" void kernel_launch(void* const* d_in, const int* in_sizes, int n_in,
                              void* d_out, int out_size, void* d_ws, size_t ws_size,
                              hipStream_t stream) {
    const float* x_user   = (const float*)d_in[0];
    const float* x_rest   = (const float*)d_in[1];
    const int*   rev_src  = (const int*)d_in[2];
    const int*   rev_dst  = (const int*)d_in[3];
    const int*   near_src = (const int*)d_in[4];
    const int*   near_dst = (const int*)d_in[5];
    const float* Win_user = (const float*)d_in[6];
    const float* Win_rest = (const float*)d_in[7];
    const float* W1_ur = (const float*)d_in[8];  const float* b1_ur = (const float*)d_in[9];
    const float* W1_ru = (const float*)d_in[10]; const float* b1_ru = (const float*)d_in[11];
    const float* W1_rr = (const float*)d_in[12]; const float* b1_rr = (const float*)d_in[13];
    const float* W2_ur = (const float*)d_in[14]; const float* b2_ur = (const float*)d_in[15];
    const float* W2_ru = (const float*)d_in[16]; const float* b2_ru = (const float*)d_in[17];
    const float* W2_rr = (const float*)d_in[18]; const float* b2_rr = (const float*)d_in[19];
    const float* Wout_user = (const float*)d_in[20];
    const float* Wout_rest = (const float*)d_in[21];

    // ---- workspace layout ----
    _Float16* p = (_Float16*)d_ws;
    _Float16* xhu = p;                 p += (size_t)MU_PAD * D_IN;
    _Float16* xhr = p;                 p += (size_t)MR_PAD * D_IN;
    _Float16* h_u = p;                 p += (size_t)MU_PAD * HID;
    _Float16* h_r = p;                 p += (size_t)MR_PAD * HID;
    _Float16* hwu = p;                 p += (size_t)MU_PAD * HID;
    _Float16* hwa = p;                 p += (size_t)MR_PAD * HID;
    _Float16* hwb = p;                 p += (size_t)MR_PAD * HID;
    _Float16* wtin_u = p;              p += 256 * 512;
    _Float16* wtin_r = p;              p += 256 * 512;
    _Float16* wt1ur = p;               p += 256 * 256;
    _Float16* wt1ru = p;               p += 256 * 256;
    _Float16* wt1rr = p;               p += 256 * 256;
    _Float16* wt2ur = p;               p += 256 * 256;
    _Float16* wt2ru = p;               p += 256 * 256;
    _Float16* wt2rr = p;               p += 256 * 256;
    _Float16* wtout_u = p;             p += 256 * 256;
    _Float16* wtout_r = p;             p += 256 * 256;
    float* inv_us = (float*)p;         // MU_PAD (pad entries poison: only feed pad rows)
    float* inv_rd = inv_us + MU_PAD;   // MR_PAD
    float* inv_ns = inv_rd + MR_PAD;
    float* inv_nd = inv_ns + MR_PAD;
    int* cnt_ur = (int*)(inv_nd + MR_PAD);  // N_REST
    int* cnt_ru = cnt_ur + N_REST;          // N_USER
    int* cnt_rr = cnt_ru + N_USER;          // N_REST
    int* cnt_ns = cnt_rr + N_REST;          // N_REST
    int* ptr_ur = cnt_ns + N_REST;          // N_REST+1
    int* ptr_ru = ptr_ur + N_REST + 1;      // N_USER+1
    int* ptr_rr = ptr_ru + N_USER + 1;      // N_REST+1
    int* csr_ur = ptr_rr + N_REST + 1;      // E_REV
    int* csr_ru = csr_ur + E_REV;           // E_REV
    int* csr_rr = csr_ru + E_REV;           // E_NEAR

    // ---- CSR build + norms ----
    hipMemsetAsync(cnt_ur, 0, (size_t)(3 * N_REST + N_USER) * sizeof(int), stream);
    count_pair<<<ceil_div(E_REV, 256), 256, 0, stream>>>(rev_src, rev_dst, cnt_ru, cnt_ur, E_REV);
    count_pair<<<ceil_div(E_NEAR, 256), 256, 0, stream>>>(near_src, near_dst, cnt_ns, cnt_rr, E_NEAR);
    inv_all<<<ceil_div(N_USER, 256), 256, 0, stream>>>(cnt_ru, cnt_ur, cnt_ns, cnt_rr,
                                                       inv_us, inv_rd, inv_ns, inv_nd);
    scan_excl<<<1, 1024, 0, stream>>>(cnt_ur, ptr_ur, N_REST);
    scan_excl<<<1, 1024, 0, stream>>>(cnt_ru, ptr_ru, N_USER);
    scan_excl<<<1, 1024, 0, stream>>>(cnt_rr, ptr_rr, N_REST);
    hipMemsetAsync(cnt_ur, 0, (size_t)(2 * N_REST + N_USER) * sizeof(int), stream);
    fill_rev<<<ceil_div(E_REV, 256), 256, 0, stream>>>(rev_src, rev_dst,
                                                       ptr_ur, cnt_ur, csr_ur,
                                                       ptr_ru, cnt_ru, csr_ru, E_REV);
    fill_one<<<ceil_div(E_NEAR, 256), 256, 0, stream>>>(near_src, near_dst,
                                                        ptr_rr, cnt_rr, csr_rr, E_NEAR);

    // ---- f16 conversions (inputs + weights) ----
    cvt_f16<<<ceil_div(N_USER * D_IN, 256 * 8), 256, 0, stream>>>(x_user, xhu, N_USER * D_IN);
    cvt_f16<<<ceil_div(N_REST * D_IN, 256 * 8), 256, 0, stream>>>(x_rest, xhr, N_REST * D_IN);
    WJobs jb;
    jb.w[0] = Win_user; jb.wt[0] = wtin_u; jb.K[0] = 512;
    jb.w[1] = Win_rest; jb.wt[1] = wtin_r; jb.K[1] = 512;
    jb.w[2] = W1_ur; jb.wt[2] = wt1ur; jb.K[2] = 256;
    jb.w[3] = W1_ru; jb.wt[3] = wt1ru; jb.K[3] = 256;
    jb.w[4] = W1_rr; jb.wt[4] = wt1rr; jb.K[4] = 256;
    jb.w[5] = W2_ur; jb.wt[5] = wt2ur; jb.K[5] = 256;
    jb.w[6] = W2_ru; jb.wt[6] = wt2ru; jb.K[6] = 256;
    jb.w[7] = W2_rr; jb.wt[7] = wt2rr; jb.K[7] = 256;
    jb.w[8] = Wout_user; jb.wt[8] = wtout_u; jb.K[8] = 256;
    jb.w[9] = Wout_rest; jb.wt[9] = wtout_r; jb.K[9] = 256;
    wprep<<<dim3(512, 10), 256, 0, stream>>>(jb);

    const dim3 gu(MU_PAD / 128, 2), gr_(MR_PAD / 128, 2);

    // ---- input projections (raw, feed layer-1 GEMMs) ----
    gemm_f16<false, true><<<gu, 256, 0, stream>>>(xhu, wtin_u, h_u, nullptr, N_USER, D_IN);
    gemm_f16<false, true><<<gr_, 256, 0, stream>>>(xhr, wtin_r, h_r, nullptr, N_REST, D_IN);

    // ---- two HeteroConv layers ----
    for (int layer = 0; layer < 2; layer++) {
        const _Float16 *Wur, *Wru, *Wrr;
        const float *bur, *bru, *brr;
        if (layer == 0) { Wur = wt1ur; Wru = wt1ru; Wrr = wt1rr; bur = b1_ur; bru = b1_ru; brr = b1_rr; }
        else            { Wur = wt2ur; Wru = wt2ru; Wrr = wt2rr; bur = b2_ur; bru = b2_ru; brr = b2_rr; }

        gemm_f16<true, true><<<gu, 256, 0, stream>>>(h_u, Wur, hwu, inv_us, N_USER, HID);
        gemm_f16<true, true><<<gr_, 256, 0, stream>>>(h_r, Wrr, hwa, inv_ns, N_REST, HID);
        gemm_f16<true, true><<<gr_, 256, 0, stream>>>(h_r, Wru, hwb, inv_rd, N_REST, HID);

        rest_agg<<<ceil_div(N_REST * 64, 256), 256, 0, stream>>>(ptr_ur, csr_ur, hwu,
                                                                 ptr_rr, csr_rr, hwa,
                                                                 inv_rd, inv_nd, bur, brr, h_r);
        user_agg<<<ceil_div(N_USER * 64, 256), 256, 0, stream>>>(ptr_ru, csr_ru, hwb,
                                                                 inv_us, bru, h_u);
    }

    // ---- output projections (fp32 out) ----
    float* out_user = (float*)d_out;
    float* out_rest = out_user + (size_t)N_USER * HID;
    gemm_f16<false, false><<<gu, 256, 0, stream>>>(h_u, wtout_u, out_user, nullptr, N_USER, HID);
    gemm_f16<false, false><<<gr_, 256, 0, stream>>>(h_r, wtout_r, out_rest, nullptr, N_REST, HID);
}

// Round 4
// 640.797 us; speedup vs baseline: 14.7063x; 1.4009x over previous
//
#include <hip/hip_runtime.h>

#define N_USER 50000
#define N_REST 20000
#define D_IN   512
#define HID    256
#define E_REV  500000
#define E_NEAR 250000
#define MU_PAD 50048   // ceil(50000/128)*128
#define MR_PAD 20096   // ceil(20000/128)*128

static inline int ceil_div(int a, int b) { return (a + b - 1) / b; }

typedef _Float16 f16x8 __attribute__((ext_vector_type(8)));
typedef _Float16 f16x4 __attribute__((ext_vector_type(4)));
typedef float    f32x4 __attribute__((ext_vector_type(4)));

typedef const __attribute__((address_space(1))) void* gaddr_t;
typedef __attribute__((address_space(3))) void*       saddr_t;

// ---------------------------------------------------------------------------
// Batched f16 MFMA GEMM: per-z job, C[M,256] = A[M,K]f16 @ Bt[256,K]f16^T
// BM=128, BN=128, BK=32; 4 waves/block. fp32 accumulate.
// ---------------------------------------------------------------------------
struct GJobs {
    const _Float16* A[3];
    const _Float16* Bt[3];
    void* C[3];
    const float* S[3];
    int MB[3];      // number of row-blocks for this job (early-exit guard)
    int Mreal[3];   // real row count (guard for fp32 output)
};

template<bool SCALE, bool OUT16>
__global__ __launch_bounds__(256) void gemm_f16(GJobs jb, int K) {
    const int z = blockIdx.z;
    if ((int)blockIdx.x >= jb.MB[z]) return;
    const _Float16* __restrict__ A  = jb.A[z];
    const _Float16* __restrict__ Bt = jb.Bt[z];
    void* __restrict__ Cout = jb.C[z];
    const float* __restrict__ S = jb.S[z];
    const int M = jb.Mreal[z];

    __shared__ _Float16 As[128][32];
    __shared__ _Float16 Bs[128][32];

    const int tid  = threadIdx.x;
    const int wave = tid >> 6, lane = tid & 63;
    const int bm = blockIdx.x * 128;
    const int bn = blockIdx.y * 128;

    const int srow = lane >> 2;
    const int scol = (lane & 3) * 8;

    const _Float16* Ag0 = A  + (size_t)(bm + wave * 16 + srow) * K + scol;
    const _Float16* Ag1 = Ag0 + (size_t)64 * K;
    const _Float16* Bg0 = Bt + (size_t)(bn + wave * 16 + srow) * K + scol;
    const _Float16* Bg1 = Bg0 + (size_t)64 * K;
    _Float16* lA0 = &As[wave * 16][0];
    _Float16* lA1 = &As[wave * 16 + 64][0];
    _Float16* lB0 = &Bs[wave * 16][0];
    _Float16* lB1 = &Bs[wave * 16 + 64][0];

    f32x4 acc[2][8];
#pragma unroll
    for (int i = 0; i < 2; i++)
#pragma unroll
        for (int j = 0; j < 8; j++) acc[i][j] = (f32x4){0.f, 0.f, 0.f, 0.f};

    const int fm = wave * 32 + (lane & 15);
    const int fn = lane & 15;
    const int qk = (lane >> 4) * 8;

    for (int k0 = 0; k0 < K; k0 += 32) {
        __builtin_amdgcn_global_load_lds((gaddr_t)(Ag0 + k0), (saddr_t)lA0, 16, 0, 0);
        __builtin_amdgcn_global_load_lds((gaddr_t)(Ag1 + k0), (saddr_t)lA1, 16, 0, 0);
        __builtin_amdgcn_global_load_lds((gaddr_t)(Bg0 + k0), (saddr_t)lB0, 16, 0, 0);
        __builtin_amdgcn_global_load_lds((gaddr_t)(Bg1 + k0), (saddr_t)lB1, 16, 0, 0);
        __syncthreads();

        f16x8 af[2], bf[8];
        af[0] = *(const f16x8*)&As[fm][qk];
        af[1] = *(const f16x8*)&As[fm + 16][qk];
#pragma unroll
        for (int j = 0; j < 8; j++)
            bf[j] = *(const f16x8*)&Bs[j * 16 + fn][qk];

#pragma unroll
        for (int i = 0; i < 2; i++)
#pragma unroll
            for (int j = 0; j < 8; j++)
                acc[i][j] = __builtin_amdgcn_mfma_f32_16x16x32_f16(af[i], bf[j], acc[i][j], 0, 0, 0);
        __syncthreads();
    }

#pragma unroll
    for (int i = 0; i < 2; i++) {
        int row0 = bm + wave * 32 + i * 16 + (lane >> 4) * 4;
#pragma unroll
        for (int j = 0; j < 8; j++) {
            int col = bn + j * 16 + (lane & 15);
#pragma unroll
            for (int rr = 0; rr < 4; rr++) {
                int gr = row0 + rr;
                float v = acc[i][j][rr];
                if (SCALE) v *= S[gr];
                if (OUT16) {
                    ((_Float16*)Cout)[(size_t)gr * HID + col] = (_Float16)v;
                } else {
                    if (gr < M) ((float*)Cout)[(size_t)gr * HID + col] = v;
                }
            }
        }
    }
}

// ---------------------------------------------------------------------------
// fp32 -> f16 conversion, both inputs in one launch
// ---------------------------------------------------------------------------
__global__ void cvt_both(const float* __restrict__ xu, const float* __restrict__ xr,
                         _Float16* __restrict__ ou, _Float16* __restrict__ orr) {
    int i = (blockIdx.x * blockDim.x + threadIdx.x) * 8;
    const float* in;
    _Float16* out;
    if (i < N_USER * D_IN) { in = xu + i; out = ou + i; }
    else {
        int j = i - N_USER * D_IN;
        if (j >= N_REST * D_IN) return;
        in = xr + j; out = orr + j;
    }
    float4 a = *(const float4*)in;
    float4 b = *(const float4*)(in + 4);
    f16x8 o = {(_Float16)a.x, (_Float16)a.y, (_Float16)a.z, (_Float16)a.w,
               (_Float16)b.x, (_Float16)b.y, (_Float16)b.z, (_Float16)b.w};
    *(f16x8*)out = o;
}

// Weight prep: W[K][256] fp32 -> Wt[256][K] f16 (batched over 10 matrices)
struct WJobs { const float* w[10]; _Float16* wt[10]; int K[10]; };
__global__ void wprep(WJobs jb) {
    int m = blockIdx.y;
    const float* w = jb.w[m];
    _Float16* wt = jb.wt[m];
    int K = jb.K[m];
    int o = blockIdx.x * 256 + threadIdx.x;
    if (o >= K * 256) return;
    int n = (K == 512) ? (o >> 9) : (o >> 8);
    int k = o & (K - 1);
    wt[o] = (_Float16)w[(size_t)k * 256 + n];
}

// ---------------------------------------------------------------------------
// CSR build: count(+slot) -> scan -> atomic-free fill
// ---------------------------------------------------------------------------
__global__ void count_slots(const int* __restrict__ rsrc, const int* __restrict__ rdst,
                            const int* __restrict__ nsrc, const int* __restrict__ ndst,
                            int* __restrict__ cnt_ur, int* __restrict__ cnt_ru,
                            int* __restrict__ cnt_rr, int* __restrict__ cnt_ns,
                            int* __restrict__ slot_ur, int* __restrict__ slot_ru,
                            int* __restrict__ slot_rr) {
    int e = blockIdx.x * blockDim.x + threadIdx.x;
    if (e < E_REV) {
        int s = rsrc[e], d = rdst[e];
        slot_ur[e] = atomicAdd(&cnt_ur[d], 1);
        slot_ru[e] = atomicAdd(&cnt_ru[s], 1);
    } else {
        int e2 = e - E_REV;
        if (e2 >= E_NEAR) return;
        int s = nsrc[e2], d = ndst[e2];
        atomicAdd(&cnt_ns[s], 1);
        slot_rr[e2] = atomicAdd(&cnt_rr[d], 1);
    }
}

__global__ void fill_all(const int* __restrict__ rsrc, const int* __restrict__ rdst,
                         const int* __restrict__ nsrc, const int* __restrict__ ndst,
                         const int* __restrict__ ptr_ur, const int* __restrict__ ptr_ru,
                         const int* __restrict__ ptr_rr,
                         const int* __restrict__ slot_ur, const int* __restrict__ slot_ru,
                         const int* __restrict__ slot_rr,
                         int* __restrict__ csr_ur, int* __restrict__ csr_ru,
                         int* __restrict__ csr_rr) {
    int e = blockIdx.x * blockDim.x + threadIdx.x;
    if (e < E_REV) {
        int s = rsrc[e], d = rdst[e];
        csr_ur[ptr_ur[d] + slot_ur[e]] = s;
        csr_ru[ptr_ru[s] + slot_ru[e]] = d;
    } else {
        int e2 = e - E_REV;
        if (e2 >= E_NEAR) return;
        csr_rr[ptr_rr[ndst[e2]] + slot_rr[e2]] = nsrc[e2];
    }
}

__device__ __forceinline__ float inv_deg(int c, float add) {
    float d = (float)c + add;
    return (d > 0.f) ? rsqrtf(d) : 0.f;
}

__global__ void inv_all(const int* __restrict__ cnt_ru, const int* __restrict__ cnt_ur,
                        const int* __restrict__ cnt_ns, const int* __restrict__ cnt_rr,
                        float* __restrict__ inv_us, float* __restrict__ inv_rd,
                        float* __restrict__ inv_ns, float* __restrict__ inv_nd) {
    int i = blockIdx.x * blockDim.x + threadIdx.x;
    if (i < N_USER) inv_us[i] = inv_deg(cnt_ru[i], 0.f);
    if (i < N_REST) {
        inv_rd[i] = inv_deg(cnt_ur[i], 0.f);
        inv_ns[i] = inv_deg(cnt_ns[i], 1.f);
        inv_nd[i] = inv_deg(cnt_rr[i], 1.f);
    }
}

// 3 independent exclusive scans, one block each; 4 elements/thread per pass.
struct ScanJobs { const int* cnt[3]; int* ptr[3]; int n[3]; };
__global__ __launch_bounds__(1024) void scan3(ScanJobs jb) {
    const int* cnt = jb.cnt[blockIdx.x];
    int* ptr = jb.ptr[blockIdx.x];
    const int n = jb.n[blockIdx.x];          // divisible by 4
    __shared__ int wsum[16];
    __shared__ int carry_s;
    const int tid = threadIdx.x, lane = tid & 63, wid = tid >> 6;
    if (tid == 0) carry_s = 0;
    __syncthreads();
    for (int base = 0; base < n; base += 4096) {
        int i0 = base + tid * 4;
        int4 v = make_int4(0, 0, 0, 0);
        if (i0 < n) v = *(const int4*)&cnt[i0];
        int s = v.x + v.y + v.z + v.w;
        int x = s;
#pragma unroll
        for (int off = 1; off < 64; off <<= 1) {
            int y = __shfl_up(x, off, 64);
            if (lane >= off) x += y;
        }
        if (lane == 63) wsum[wid] = x;
        __syncthreads();
        if (wid == 0 && lane < 16) {
            int w = wsum[lane];
#pragma unroll
            for (int off = 1; off < 16; off <<= 1) {
                int y = __shfl_up(w, off, 16);
                if (lane >= off) w += y;
            }
            wsum[lane] = w;
        }
        __syncthreads();
        int wave_off = (wid > 0) ? wsum[wid - 1] : 0;
        if (i0 < n) {
            int e = carry_s + wave_off + (x - s);
            int4 o = make_int4(e, e + v.x, e + v.x + v.y, e + v.x + v.y + v.z);
            *(int4*)&ptr[i0] = o;
        }
        __syncthreads();
        if (tid == 0) carry_s += wsum[15];
        __syncthreads();
    }
    if (threadIdx.x == 0) ptr[n] = carry_s;
}

// ---------------------------------------------------------------------------
// Fused aggregation: waves [0,N_REST) do rest rows, [N_REST, N_REST+N_USER)
// user rows. Lane l holds cols 4l..4l+3; fp32 accumulate; relu fused.
// ---------------------------------------------------------------------------
__device__ __forceinline__ void acc_rows16(const int* __restrict__ csr, int beg, int end,
                                           const _Float16* __restrict__ hw, int c, f32x4& acc) {
    int e = beg;
    for (; e + 3 < end; e += 4) {
        int s0 = csr[e], s1 = csr[e + 1], s2 = csr[e + 2], s3 = csr[e + 3];
        f16x4 v0 = *(const f16x4*)&hw[(size_t)s0 * HID + c];
        f16x4 v1 = *(const f16x4*)&hw[(size_t)s1 * HID + c];
        f16x4 v2 = *(const f16x4*)&hw[(size_t)s2 * HID + c];
        f16x4 v3 = *(const f16x4*)&hw[(size_t)s3 * HID + c];
#pragma unroll
        for (int r = 0; r < 4; r++)
            acc[r] += ((float)v0[r] + (float)v1[r]) + ((float)v2[r] + (float)v3[r]);
    }
    for (; e < end; e++) {
        f16x4 v = *(const f16x4*)&hw[(size_t)csr[e] * HID + c];
#pragma unroll
        for (int r = 0; r < 4; r++) acc[r] += (float)v[r];
    }
}

__global__ __launch_bounds__(256) void agg_all(
    const int* __restrict__ ptr_ur, const int* __restrict__ csr_ur, const _Float16* __restrict__ hwu,
    const int* __restrict__ ptr_rr, const int* __restrict__ csr_rr, const _Float16* __restrict__ hwa,
    const int* __restrict__ ptr_ru, const int* __restrict__ csr_ru, const _Float16* __restrict__ hwb,
    const float* __restrict__ inv_rd, const float* __restrict__ inv_nd, const float* __restrict__ inv_us,
    const float* __restrict__ b_ur, const float* __restrict__ b_rr, const float* __restrict__ b_ru,
    _Float16* __restrict__ out_r, _Float16* __restrict__ out_u) {
    int w = (blockIdx.x * blockDim.x + threadIdx.x) >> 6;
    int c = (threadIdx.x & 63) * 4;

    if (w < N_REST) {
        int row = w;
        f32x4 au = (f32x4){0.f, 0.f, 0.f, 0.f};
        acc_rows16(csr_ur, ptr_ur[row], ptr_ur[row + 1], hwu, c, au);

        f32x4 ar;
        {   // self-loop (hwa pre-scaled by inv_ns)
            f16x4 v = *(const f16x4*)&hwa[(size_t)row * HID + c];
#pragma unroll
            for (int r = 0; r < 4; r++) ar[r] = (float)v[r];
        }
        acc_rows16(csr_rr, ptr_rr[row], ptr_rr[row + 1], hwa, c, ar);

        float sd = inv_rd[row], sn = inv_nd[row];
        f32x4 bu = *(const f32x4*)&b_ur[c];
        f32x4 br = *(const f32x4*)&b_rr[c];
        f16x4 oh;
#pragma unroll
        for (int r = 0; r < 4; r++)
            oh[r] = (_Float16)fmaxf(bu[r] + br[r] + sd * au[r] + sn * ar[r], 0.f);
        *(f16x4*)&out_r[(size_t)row * HID + c] = oh;
    } else {
        int row = w - N_REST;
        if (row >= N_USER) return;
        f32x4 a = (f32x4){0.f, 0.f, 0.f, 0.f};
        acc_rows16(csr_ru, ptr_ru[row], ptr_ru[row + 1], hwb, c, a);

        float su = inv_us[row];
        f32x4 b = *(const f32x4*)&b_ru[c];
        f16x4 oh;
#pragma unroll
        for (int r = 0; r < 4; r++)
            oh[r] = (_Float16)fmaxf(b[r] + su * a[r], 0.f);
        *(f16x4*)&out_u[(size_t)row * HID + c] = oh;
    }
}

// ---------------------------------------------------------------------------
extern "C" void kernel_launch(void* const* d_in, const int* in_sizes, int n_in,
                              void* d_out, int out_size, void* d_ws, size_t ws_size,
                              hipStream_t stream) {
    const float* x_user   = (const float*)d_in[0];
    const float* x_rest   = (const float*)d_in[1];
    const int*   rev_src  = (const int*)d_in[2];
    const int*   rev_dst  = (const int*)d_in[3];
    const int*   near_src = (const int*)d_in[4];
    const int*   near_dst = (const int*)d_in[5];
    const float* Win_user = (const float*)d_in[6];
    const float* Win_rest = (const float*)d_in[7];
    const float* W1_ur = (const float*)d_in[8];  const float* b1_ur = (const float*)d_in[9];
    const float* W1_ru = (const float*)d_in[10]; const float* b1_ru = (const float*)d_in[11];
    const float* W1_rr = (const float*)d_in[12]; const float* b1_rr = (const float*)d_in[13];
    const float* W2_ur = (const float*)d_in[14]; const float* b2_ur = (const float*)d_in[15];
    const float* W2_ru = (const float*)d_in[16]; const float* b2_ru = (const float*)d_in[17];
    const float* W2_rr = (const float*)d_in[18]; const float* b2_rr = (const float*)d_in[19];
    const float* Wout_user = (const float*)d_in[20];
    const float* Wout_rest = (const float*)d_in[21];

    // ---- workspace layout (hwu/hwa/hwb alias the dead xhu/xhr region) ----
    _Float16* p = (_Float16*)d_ws;
    _Float16* xhu = p;                 p += (size_t)MU_PAD * D_IN;   // 51.2 MB
    _Float16* xhr = p;                 p += (size_t)MR_PAD * D_IN;   // 20.6 MB
    _Float16* hwu = xhu;                                             // alias: MU_PAD*HID
    _Float16* hwa = hwu + (size_t)MU_PAD * HID;                      // MR_PAD*HID
    _Float16* hwb = hwa + (size_t)MR_PAD * HID;                      // MR_PAD*HID (46.2<71.8 MB)
    _Float16* h_u = p;                 p += (size_t)MU_PAD * HID;
    _Float16* h_r = p;                 p += (size_t)MR_PAD * HID;
    _Float16* wtin_u = p;              p += 256 * 512;
    _Float16* wtin_r = p;              p += 256 * 512;
    _Float16* wt1ur = p;               p += 256 * 256;
    _Float16* wt1ru = p;               p += 256 * 256;
    _Float16* wt1rr = p;               p += 256 * 256;
    _Float16* wt2ur = p;               p += 256 * 256;
    _Float16* wt2ru = p;               p += 256 * 256;
    _Float16* wt2rr = p;               p += 256 * 256;
    _Float16* wtout_u = p;             p += 256 * 256;
    _Float16* wtout_r = p;             p += 256 * 256;
    float* inv_us = (float*)p;         // MU_PAD
    float* inv_rd = inv_us + MU_PAD;   // MR_PAD
    float* inv_ns = inv_rd + MR_PAD;
    float* inv_nd = inv_ns + MR_PAD;
    int* cnt_ur = (int*)(inv_nd + MR_PAD);  // N_REST
    int* cnt_ru = cnt_ur + N_REST;          // N_USER
    int* cnt_rr = cnt_ru + N_USER;          // N_REST
    int* cnt_ns = cnt_rr + N_REST;          // N_REST
    int* ptr_ur = cnt_ns + N_REST;          // N_REST+1
    int* ptr_ru = ptr_ur + N_REST + 4;      // N_USER+1 (pad for int4 alignment)
    int* ptr_rr = ptr_ru + N_USER + 4;      // N_REST+1
    int* csr_ur = ptr_rr + N_REST + 4;      // E_REV
    int* csr_ru = csr_ur + E_REV;           // E_REV
    int* csr_rr = csr_ru + E_REV;           // E_NEAR
    int* slot_ur = csr_rr + E_NEAR;         // E_REV
    int* slot_ru = slot_ur + E_REV;         // E_REV
    int* slot_rr = slot_ru + E_REV;         // E_NEAR

    const int E_TOT = E_REV + E_NEAR;

    // ---- CSR build ----
    hipMemsetAsync(cnt_ur, 0, (size_t)(3 * N_REST + N_USER) * sizeof(int), stream);
    count_slots<<<ceil_div(E_TOT, 256), 256, 0, stream>>>(rev_src, rev_dst, near_src, near_dst,
                                                          cnt_ur, cnt_ru, cnt_rr, cnt_ns,
                                                          slot_ur, slot_ru, slot_rr);
    inv_all<<<ceil_div(N_USER, 256), 256, 0, stream>>>(cnt_ru, cnt_ur, cnt_ns, cnt_rr,
                                                       inv_us, inv_rd, inv_ns, inv_nd);
    ScanJobs sj;
    sj.cnt[0] = cnt_ur; sj.ptr[0] = ptr_ur; sj.n[0] = N_REST;
    sj.cnt[1] = cnt_ru; sj.ptr[1] = ptr_ru; sj.n[1] = N_USER;
    sj.cnt[2] = cnt_rr; sj.ptr[2] = ptr_rr; sj.n[2] = N_REST;
    scan3<<<3, 1024, 0, stream>>>(sj);
    fill_all<<<ceil_div(E_TOT, 256), 256, 0, stream>>>(rev_src, rev_dst, near_src, near_dst,
                                                       ptr_ur, ptr_ru, ptr_rr,
                                                       slot_ur, slot_ru, slot_rr,
                                                       csr_ur, csr_ru, csr_rr);

    // ---- f16 conversions ----
    cvt_both<<<ceil_div((N_USER + N_REST) * D_IN, 256 * 8), 256, 0, stream>>>(x_user, x_rest, xhu, xhr);
    WJobs jb;
    jb.w[0] = Win_user; jb.wt[0] = wtin_u; jb.K[0] = 512;
    jb.w[1] = Win_rest; jb.wt[1] = wtin_r; jb.K[1] = 512;
    jb.w[2] = W1_ur; jb.wt[2] = wt1ur; jb.K[2] = 256;
    jb.w[3] = W1_ru; jb.wt[3] = wt1ru; jb.K[3] = 256;
    jb.w[4] = W1_rr; jb.wt[4] = wt1rr; jb.K[4] = 256;
    jb.w[5] = W2_ur; jb.wt[5] = wt2ur; jb.K[5] = 256;
    jb.w[6] = W2_ru; jb.wt[6] = wt2ru; jb.K[6] = 256;
    jb.w[7] = W2_rr; jb.wt[7] = wt2rr; jb.K[7] = 256;
    jb.w[8] = Wout_user; jb.wt[8] = wtout_u; jb.K[8] = 256;
    jb.w[9] = Wout_rest; jb.wt[9] = wtout_r; jb.K[9] = 256;
    wprep<<<dim3(512, 10), 256, 0, stream>>>(jb);

    const int MBU = MU_PAD / 128, MBR = MR_PAD / 128;

    // ---- input projections (batched: 2 jobs) ----
    {
        GJobs g;
        g.A[0] = xhu; g.Bt[0] = wtin_u; g.C[0] = h_u; g.S[0] = nullptr; g.MB[0] = MBU; g.Mreal[0] = N_USER;
        g.A[1] = xhr; g.Bt[1] = wtin_r; g.C[1] = h_r; g.S[1] = nullptr; g.MB[1] = MBR; g.Mreal[1] = N_REST;
        g.A[2] = xhu; g.Bt[2] = wtin_u; g.C[2] = h_u; g.S[2] = nullptr; g.MB[2] = 0;   g.Mreal[2] = 0;
        gemm_f16<false, true><<<dim3(MBU, 2, 2), 256, 0, stream>>>(g, D_IN);
    }

    // ---- two HeteroConv layers ----
    for (int layer = 0; layer < 2; layer++) {
        const _Float16 *Wur, *Wru, *Wrr;
        const float *bur, *bru, *brr;
        if (layer == 0) { Wur = wt1ur; Wru = wt1ru; Wrr = wt1rr; bur = b1_ur; bru = b1_ru; brr = b1_rr; }
        else            { Wur = wt2ur; Wru = wt2ru; Wrr = wt2rr; bur = b2_ur; bru = b2_ru; brr = b2_rr; }

        GJobs g;
        g.A[0] = h_u; g.Bt[0] = Wur; g.C[0] = hwu; g.S[0] = inv_us; g.MB[0] = MBU; g.Mreal[0] = N_USER;
        g.A[1] = h_r; g.Bt[1] = Wrr; g.C[1] = hwa; g.S[1] = inv_ns; g.MB[1] = MBR; g.Mreal[1] = N_REST;
        g.A[2] = h_r; g.Bt[2] = Wru; g.C[2] = hwb; g.S[2] = inv_rd; g.MB[2] = MBR; g.Mreal[2] = N_REST;
        gemm_f16<true, true><<<dim3(MBU, 2, 3), 256, 0, stream>>>(g, HID);

        agg_all<<<ceil_div((N_REST + N_USER) * 64, 256), 256, 0, stream>>>(
            ptr_ur, csr_ur, hwu, ptr_rr, csr_rr, hwa, ptr_ru, csr_ru, hwb,
            inv_rd, inv_nd, inv_us, bur, brr, bru, h_r, h_u);
    }

    // ---- output projections (batched: 2 jobs, fp32 out) ----
    float* out_user = (float*)d_out;
    float* out_rest = out_user + (size_t)N_USER * HID;
    {
        GJobs g;
        g.A[0] = h_u; g.Bt[0] = wtout_u; g.C[0] = out_user; g.S[0] = nullptr; g.MB[0] = MBU; g.Mreal[0] = N_USER;
        g.A[1] = h_r; g.Bt[1] = wtout_r; g.C[1] = out_rest; g.S[1] = nullptr; g.MB[1] = MBR; g.Mreal[1] = N_REST;
        g.A[2] = h_u; g.Bt[2] = wtout_u; g.C[2] = out_user; g.S[2] = nullptr; g.MB[2] = 0;   g.Mreal[2] = 0;
        gemm_f16<false, false><<<dim3(MBU, 2, 2), 256, 0, stream>>>(g, HID);
    }
}